// Round 5
// baseline (480.640 us; speedup 1.0000x reference)
//
#include <hip/hip_runtime.h>
#include <hip/hip_bf16.h>
#include <math.h>

#define NTOK 65536
#define DIM  128
#define NE   9
#define TOPK 3
#define ALPHA_C 1e-4f

using bf16x8 = __attribute__((ext_vector_type(8))) short;
using f32x4  = __attribute__((ext_vector_type(4))) float;

// ws layout (bytes)
static constexpr size_t OFF_MG   = 0;        // 32 f32
static constexpr size_t OFF_CNT  = 128;      // 9 u32
static constexpr size_t OFF_GSUM = 192;      // 9 f32
static constexpr size_t OFF_SB   = 256;      // 9*128 f32 -> 4864
static constexpr size_t OFF_W1T  = 4864;     // 9*128*128 bf16 -> 299776
static constexpr size_t OFF_W2T  = 299776;   // -> 594688

__device__ __forceinline__ unsigned short f2bf(float f) {
    __hip_bfloat16 h = __float2bfloat16(f);
    return *reinterpret_cast<unsigned short*>(&h);
}

// ---------------- K1: market = relu(x@Wr_w + Wr_b); mg[m] = sum_n market[n][m]*Wl_w[n]
__global__ __launch_bounds__(256) void k_market(const float* __restrict__ x,
    const float* __restrict__ Wrw, const float* __restrict__ Wrb,
    const float* __restrict__ Wlw, float* __restrict__ mg_acc)
{
    __shared__ float xs[64 * 128];
    __shared__ float wr[128 * 32];
    __shared__ float part[256][8];
    int tid = threadIdx.x;
    int base = blockIdx.x * 64;

    const float4* x4 = (const float4*)x + (size_t)base * 32;
    float4* xs4 = (float4*)xs;
    for (int i = tid; i < 64 * 32; i += 256) xs4[i] = x4[i];
    const float4* w4 = (const float4*)Wrw;
    float4* wr4 = (float4*)wr;
    for (int i = tid; i < 128 * 32 / 4; i += 256) wr4[i] = w4[i];
    __syncthreads();

    int tok = tid >> 2, sub = tid & 3, m0 = sub * 8;
    float acc[8];
    #pragma unroll
    for (int k = 0; k < 8; ++k) acc[k] = 0.f;
    for (int d = 0; d < 128; ++d) {
        float xv = xs[tok * 128 + d];
        #pragma unroll
        for (int k = 0; k < 8; ++k) acc[k] += xv * wr[d * 32 + m0 + k];
    }
    float wl = Wlw[base + tok];
    #pragma unroll
    for (int k = 0; k < 8; ++k) {
        float v = acc[k] + Wrb[m0 + k];
        part[tid][k] = (v > 0.f ? v : 0.f) * wl;
    }
    __syncthreads();
    if (tid < 32) {
        int m = tid;
        float s = 0.f;
        for (int t = 0; t < 64; ++t) s += part[t * 4 + (m >> 3)][m & 7];
        atomicAdd(&mg_acc[m], s);
    }
}

// ---------------- K_prepw: W1x, W2 -> bf16 transposed [n][k] per expert, (9,4) grid
__global__ __launch_bounds__(256) void k_prepw(const float* __restrict__ W1,
    const float* __restrict__ W2, unsigned short* __restrict__ W1T,
    unsigned short* __restrict__ W2T)
{
    __shared__ float t1[32][129];
    __shared__ float t2[32][129];
    int e = blockIdx.x;
    int kb = blockIdx.y * 32;
    int tid = threadIdx.x;
    const float* W1e = W1 + (size_t)e * 20480;   // [160][128], first 128 rows
    const float* W2e = W2 + (size_t)e * 16384;   // [128][128]
    unsigned short* o1 = W1T + (size_t)e * 16384;
    unsigned short* o2 = W2T + (size_t)e * 16384;
    for (int i = tid; i < 32 * 128; i += 256) {
        int k = i >> 7, n = i & 127;
        t1[k][n] = W1e[(size_t)(kb + k) * 128 + n];
        t2[k][n] = W2e[(size_t)(kb + k) * 128 + n];
    }
    __syncthreads();
    for (int i = tid; i < 128 * 32; i += 256) {
        int n = i >> 5, kk = i & 31;
        o1[(size_t)n * 128 + kb + kk] = f2bf(t1[kk][n]);
        o2[(size_t)n * 128 + kb + kk] = f2bf(t2[kk][n]);
    }
}

// ---------------- K4: style_bias[e][h]
__global__ void k_stylebias(const float* __restrict__ styles, const float* __restrict__ W1,
                            const float* __restrict__ b1, float* __restrict__ sb)
{
    int e = blockIdx.x, h = threadIdx.x;
    float acc = b1[e * 128 + h];
    for (int s = 0; s < 32; ++s)
        acc += styles[e * 32 + s] * W1[(size_t)e * 20480 + (size_t)(128 + s) * 128 + h];
    sb[e * 128 + h] = acc;
}

// ---------------- K3: aux loss scalar
__global__ void k_aux(const unsigned* __restrict__ cnt, const float* __restrict__ gsum,
                      float* __restrict__ out)
{
    float a = 0.f;
    for (int e = 0; e < 9; ++e) {
        float fi = (float)cnt[e] * ((float)NE / ((float)TOPK * (float)NTOK));
        float Pi = gsum[e] / (float)NTOK;
        a += fi * Pi;
    }
    out[(size_t)NTOK * DIM] = ALPHA_C * a;
}

// ---------------- K_fused: router + dense 9-expert FFN + gated accumulate + store
// 64 tokens/block, 256 threads (4 waves), wave = 16 tokens x 128 cols.
// NOTE: no min-waves clamp — acc_out(32)+acc1(32)+frags need ~120+ VGPR;
// forcing 64 VGPR spilled everything to scratch (round-4: 342us, MfmaUtil 4.5%).
__global__ __launch_bounds__(256) void k_fused(const float* __restrict__ x,
    const float* __restrict__ rweights, const float* __restrict__ rb,
    const float* __restrict__ mg, const float* __restrict__ Wlb,
    const unsigned short* __restrict__ W1T, const unsigned short* __restrict__ W2T,
    const float* __restrict__ sbg, const float* __restrict__ b2g,
    unsigned* __restrict__ cnt, float* __restrict__ gsum,
    float* __restrict__ out)
{
    __shared__ unsigned short xs[64 * 128];   // 16 KB swizzled bf16 X
    __shared__ unsigned short hs[64 * 128];   // 16 KB swizzled bf16 H; router scratch overlay
    __shared__ float garr[64][12];            // dense gates (3 nonzero/row)
    __shared__ float ce[9];
    __shared__ unsigned lcount[9];
    __shared__ float lgsum[9];

    float* part = (float*)hs;                 // [64][4][9] = 2304 f32 (9216 B)
    float* rwp  = (float*)hs + 2304;          // 160*9 f32 (5760 B) -> 14976 B < 16 KB

    int tid = threadIdx.x;
    int base = blockIdx.x * 64;

    for (int i = tid; i < 160 * 9; i += 256) rwp[i] = rweights[i];
    if (tid < 9) { lcount[tid] = 0u; lgsum[tid] = 0.f; }
    __syncthreads();

    // router partials: 4 threads per token, 32 d each (f32, exact)
    int tok = tid >> 2, sub = tid & 3;
    {
        float acc[9];
        #pragma unroll
        for (int e = 0; e < 9; ++e) acc[e] = 0.f;
        const float* xrow = x + (size_t)(base + tok) * 128 + sub * 32;
        for (int d = 0; d < 32; ++d) {
            float xv = xrow[d];
            #pragma unroll
            for (int e = 0; e < 9; ++e) acc[e] += xv * rwp[(sub * 32 + d) * 9 + e];
        }
        #pragma unroll
        for (int e = 0; e < 9; ++e) part[(tok * 4 + sub) * 9 + e] = acc[e];
    }
    if (tid < 9) {
        float c = rb[tid];
        float wlb = Wlb[0];
        for (int m = 0; m < 32; ++m) c += (mg[m] + wlb) * rwp[(128 + m) * 9 + tid];
        ce[tid] = c;
    }
    // stage X -> swizzled bf16 LDS (L2-warm second read)
    {
        const float4* x4 = (const float4*)x;
        for (int i = tid; i < 64 * 32; i += 256) {
            int row = i >> 5, p = i & 31;
            float4 v = x4[(size_t)(base + row) * 32 + p];
            unsigned short u[4] = { f2bf(v.x), f2bf(v.y), f2bf(v.z), f2bf(v.w) };
            int sw = ((((p >> 1) ^ (row & 7)) << 4) | ((p & 1) << 3));
            *(ushort4*)((char*)xs + row * 256 + sw) = *(ushort4*)u;
        }
    }
    __syncthreads();

    // finalize router: one thread per token
    if (sub == 0) {
        float lg[9];
        #pragma unroll
        for (int e = 0; e < 9; ++e)
            lg[e] = ce[e] + part[(tok * 4 + 0) * 9 + e] + part[(tok * 4 + 1) * 9 + e]
                  + part[(tok * 4 + 2) * 9 + e] + part[(tok * 4 + 3) * 9 + e];
        int used = 0;
        int bi[3]; float bv[3];
        for (int k = 0; k < 3; ++k) {
            float best = -1e30f; int b = -1;
            for (int e = 0; e < 9; ++e)
                if (!((used >> e) & 1) && lg[e] > best) { best = lg[e]; b = e; }
            bi[k] = b; bv[k] = best; used |= 1 << b;
        }
        float p3[3]; float s = 0.f;
        for (int k = 0; k < 3; ++k) { p3[k] = expf(bv[k] - bv[0]); s += p3[k]; }
        #pragma unroll
        for (int e = 0; e < 12; ++e) garr[tok][e] = 0.f;
        for (int k = 0; k < 3; ++k) {
            float g = p3[k] / s;
            garr[tok][bi[k]] = g;
            atomicAdd(&lcount[bi[k]], 1u);
            atomicAdd(&lgsum[bi[k]], g);
        }
    }
    __syncthreads();   // garr ready; hs (part/rwp) free
    if (tid < 9) {
        atomicAdd(&cnt[tid], lcount[tid]);
        atomicAdd(&gsum[tid], lgsum[tid]);
    }

    int lane = tid & 63, w = tid >> 6;
    int cb = lane & 15, kq = lane >> 4;
    int arow = w * 16 + cb;

    f32x4 acc_out[8];
    #pragma unroll
    for (int n = 0; n < 8; ++n) acc_out[n] = (f32x4){0.f, 0.f, 0.f, 0.f};

    #pragma unroll 1
    for (int e = 0; e < 9; ++e) {
        const unsigned short* W1e = W1T + (size_t)e * 16384;
        const unsigned short* W2e = W2T + (size_t)e * 16384;

        f32x4 acc1[8];
        #pragma unroll
        for (int n = 0; n < 8; ++n) acc1[n] = (f32x4){0.f, 0.f, 0.f, 0.f};

        // Phase 1: H_e = relu(X @ W1x_e + sb_e) * g[:,e]
        #pragma unroll
        for (int kk = 0; kk < 4; ++kk) {
            bf16x8 a = *(const bf16x8*)((const char*)xs + arow * 256 + ((((kk * 4 + kq) ^ (arow & 7)) << 4)));
            #pragma unroll
            for (int n = 0; n < 8; ++n) {
                bf16x8 b = *(const bf16x8*)(W1e + (size_t)(n * 16 + cb) * 128 + kk * 32 + kq * 8);
                acc1[n] = __builtin_amdgcn_mfma_f32_16x16x32_bf16(a, b, acc1[n], 0, 0, 0);
            }
        }
        float gv[4];
        #pragma unroll
        for (int r = 0; r < 4; ++r) gv[r] = garr[w * 16 + kq * 4 + r][e];
        #pragma unroll
        for (int n = 0; n < 8; ++n) {
            int col = n * 16 + cb;
            float sbv = sbg[e * 128 + col];
            #pragma unroll
            for (int r = 0; r < 4; ++r) {
                int row = w * 16 + kq * 4 + r;
                float h = acc1[n][r] + sbv;
                h = (h > 0.f ? h : 0.f) * gv[r];
                int byte = col * 2;
                int sw = ((((byte >> 4) ^ (row & 7)) << 4) | (byte & 15));
                *(unsigned short*)((char*)hs + row * 256 + sw) = f2bf(h);
            }
        }
        __syncthreads();

        // Phase 2: acc_out += H_e @ W2_e   (accumulates across experts)
        #pragma unroll
        for (int kk = 0; kk < 4; ++kk) {
            bf16x8 a = *(const bf16x8*)((const char*)hs + arow * 256 + ((((kk * 4 + kq) ^ (arow & 7)) << 4)));
            #pragma unroll
            for (int n = 0; n < 8; ++n) {
                bf16x8 b = *(const bf16x8*)(W2e + (size_t)(n * 16 + cb) * 128 + kk * 32 + kq * 8);
                acc_out[n] = __builtin_amdgcn_mfma_f32_16x16x32_bf16(a, b, acc_out[n], 0, 0, 0);
            }
        }
        __syncthreads();   // hs consumed; next expert may overwrite
    }

    // epilogue: add sum_e g[t][e]*b2[e][col], store
    #pragma unroll
    for (int n = 0; n < 8; ++n) {
        int col = n * 16 + cb;
        float b2c[9];
        #pragma unroll
        for (int e = 0; e < 9; ++e) b2c[e] = b2g[e * 128 + col];
        #pragma unroll
        for (int r = 0; r < 4; ++r) {
            int row = w * 16 + kq * 4 + r;
            float bias = 0.f;
            #pragma unroll
            for (int e = 0; e < 9; ++e) bias += garr[row][e] * b2c[e];
            out[(size_t)(base + row) * 128 + col] = acc_out[n][r] + bias;
        }
    }
}

extern "C" void kernel_launch(void* const* d_in, const int* in_sizes, int n_in,
                              void* d_out, int out_size, void* d_ws, size_t ws_size,
                              hipStream_t stream) {
    const float* x      = (const float*)d_in[0];
    const float* Wrw    = (const float*)d_in[1];
    const float* Wrb    = (const float*)d_in[2];
    const float* Wlw    = (const float*)d_in[3];
    const float* Wlb    = (const float*)d_in[4];
    const float* rw     = (const float*)d_in[5];
    const float* rb     = (const float*)d_in[6];
    const float* styles = (const float*)d_in[7];
    const float* W1     = (const float*)d_in[8];
    const float* b1     = (const float*)d_in[9];
    const float* W2     = (const float*)d_in[10];
    const float* b2     = (const float*)d_in[11];
    float* out = (float*)d_out;

    char* ws = (char*)d_ws;
    float*          mg    = (float*)(ws + OFF_MG);
    unsigned*       cnt   = (unsigned*)(ws + OFF_CNT);
    float*          gsum  = (float*)(ws + OFF_GSUM);
    float*          sbp   = (float*)(ws + OFF_SB);
    unsigned short* W1T   = (unsigned short*)(ws + OFF_W1T);
    unsigned short* W2T   = (unsigned short*)(ws + OFF_W2T);

    hipMemsetAsync(ws, 0, 256, stream);   // mg, cnt, gsum

    k_market<<<1024, 256, 0, stream>>>(x, Wrw, Wrb, Wlw, mg);
    k_prepw<<<dim3(9, 4), 256, 0, stream>>>(W1, W2, W1T, W2T);
    k_stylebias<<<9, 128, 0, stream>>>(styles, W1, b1, sbp);
    k_fused<<<1024, 256, 0, stream>>>(x, rw, rb, mg, Wlb, W1T, W2T, sbp, b2,
                                      cnt, gsum, out);
    k_aux<<<1, 1, 0, stream>>>(cnt, gsum, out);
}

// Round 6
// 215.478 us; speedup vs baseline: 2.2306x; 2.2306x over previous
//
#include <hip/hip_runtime.h>
#include <hip/hip_bf16.h>
#include <math.h>

#define NTOK 65536
#define DIM  128
#define NE   9
#define TOPK 3
#define ALPHA_C 1e-4f

using bf16x8 = __attribute__((ext_vector_type(8))) short;
using f32x4  = __attribute__((ext_vector_type(4))) float;

// ws layout (bytes)
static constexpr size_t OFF_MG   = 0;        // 32 f32
static constexpr size_t OFF_CNT  = 128;      // 9 u32
static constexpr size_t OFF_GSUM = 192;      // 9 f32
static constexpr size_t OFF_SB   = 256;      // 9*128 f32 -> 4864
static constexpr size_t OFF_W1F  = 4864;     // 9*128*128 bf16 (frag-ordered) -> 299776
static constexpr size_t OFF_W2F  = 299776;   // -> 594688

__device__ __forceinline__ unsigned short f2bf(float f) {
    __hip_bfloat16 h = __float2bfloat16(f);
    return *reinterpret_cast<unsigned short*>(&h);
}

// ---------------- K1: market = relu(x@Wr_w + Wr_b); mg[m] = sum_n market[n][m]*Wl_w[n]
__global__ __launch_bounds__(256) void k_market(const float* __restrict__ x,
    const float* __restrict__ Wrw, const float* __restrict__ Wrb,
    const float* __restrict__ Wlw, float* __restrict__ mg_acc)
{
    __shared__ float xs[64 * 128];
    __shared__ float wr[128 * 32];
    __shared__ float part[256][8];
    int tid = threadIdx.x;
    int base = blockIdx.x * 64;

    const float4* x4 = (const float4*)x + (size_t)base * 32;
    float4* xs4 = (float4*)xs;
    for (int i = tid; i < 64 * 32; i += 256) xs4[i] = x4[i];
    const float4* w4 = (const float4*)Wrw;
    float4* wr4 = (float4*)wr;
    for (int i = tid; i < 128 * 32 / 4; i += 256) wr4[i] = w4[i];
    __syncthreads();

    int tok = tid >> 2, sub = tid & 3, m0 = sub * 8;
    float acc[8];
    #pragma unroll
    for (int k = 0; k < 8; ++k) acc[k] = 0.f;
    for (int d = 0; d < 128; ++d) {
        float xv = xs[tok * 128 + d];
        #pragma unroll
        for (int k = 0; k < 8; ++k) acc[k] += xv * wr[d * 32 + m0 + k];
    }
    float wl = Wlw[base + tok];
    #pragma unroll
    for (int k = 0; k < 8; ++k) {
        float v = acc[k] + Wrb[m0 + k];
        part[tid][k] = (v > 0.f ? v : 0.f) * wl;
    }
    __syncthreads();
    if (tid < 32) {
        int m = tid;
        float s = 0.f;
        for (int t = 0; t < 64; ++t) s += part[t * 4 + (m >> 3)][m & 7];
        atomicAdd(&mg_acc[m], s);
    }
}

// ---------------- K_prepw: fragment-ordered bf16 weights.
// W1F[e][n][kk][lane][j] = W1[e][kk*32+(lane>>4)*8+j][n*16+(lane&15)]   (n,kk: 8,4)
// A wave's B-frag load becomes one coalesced 1KB global_load_dwordx4.
__global__ __launch_bounds__(256) void k_prepw(const float* __restrict__ W1,
    const float* __restrict__ W2, unsigned short* __restrict__ W1F,
    unsigned short* __restrict__ W2F)
{
    int e = blockIdx.x;
    int n = blockIdx.y;
    int tid = threadIdx.x;
    int kk = tid >> 6, l = tid & 63;
    int row0 = kk * 32 + (l >> 4) * 8;
    int col  = n * 16 + (l & 15);
    const float* W1e = W1 + (size_t)e * 20480;   // [160][128]
    const float* W2e = W2 + (size_t)e * 16384;   // [128][128]
    size_t ob = (size_t)e * 16384 + n * 2048 + kk * 512 + l * 8;
    unsigned short u1[8], u2[8];
    #pragma unroll
    for (int j = 0; j < 8; ++j) {
        u1[j] = f2bf(W1e[(size_t)(row0 + j) * 128 + col]);
        u2[j] = f2bf(W2e[(size_t)(row0 + j) * 128 + col]);
    }
    *(ushort4*)(W1F + ob)     = *(ushort4*)(u1);
    *(ushort4*)(W1F + ob + 4) = *(ushort4*)(u1 + 4);
    *(ushort4*)(W2F + ob)     = *(ushort4*)(u2);
    *(ushort4*)(W2F + ob + 4) = *(ushort4*)(u2 + 4);
}

// ---------------- K4: style_bias[e][h]
__global__ void k_stylebias(const float* __restrict__ styles, const float* __restrict__ W1,
                            const float* __restrict__ b1, float* __restrict__ sb)
{
    int e = blockIdx.x, h = threadIdx.x;
    float acc = b1[e * 128 + h];
    for (int s = 0; s < 32; ++s)
        acc += styles[e * 32 + s] * W1[(size_t)e * 20480 + (size_t)(128 + s) * 128 + h];
    sb[e * 128 + h] = acc;
}

// ---------------- K3: aux loss scalar
__global__ void k_aux(const unsigned* __restrict__ cnt, const float* __restrict__ gsum,
                      float* __restrict__ out)
{
    float a = 0.f;
    for (int e = 0; e < 9; ++e) {
        float fi = (float)cnt[e] * ((float)NE / ((float)TOPK * (float)NTOK));
        float Pi = gsum[e] / (float)NTOK;
        a += fi * Pi;
    }
    out[(size_t)NTOK * DIM] = ALPHA_C * a;
}

// ---------------- K_fused: router + dense 9-expert FFN + gated accumulate + store
// 64 tokens/block, 4 waves. Wave w owns n-tiles {2w,2w+1} (32 output cols),
// all 4 M-tiles. B-loads: 8 coalesced 1KB loads per phase per wave.
__global__ __launch_bounds__(256) void k_fused(const float* __restrict__ x,
    const float* __restrict__ rweights, const float* __restrict__ rb,
    const float* __restrict__ mg, const float* __restrict__ Wlb,
    const unsigned short* __restrict__ W1F, const unsigned short* __restrict__ W2F,
    const float* __restrict__ sbg, const float* __restrict__ b2g,
    unsigned* __restrict__ cnt, float* __restrict__ gsum,
    float* __restrict__ out)
{
    __shared__ unsigned short xs[64 * 128];   // 16 KB swizzled bf16 X
    __shared__ unsigned short hs[64 * 128];   // 16 KB swizzled bf16 H; router scratch overlay
    __shared__ float garr[64][12];
    __shared__ float ce[9];
    __shared__ unsigned lcount[9];
    __shared__ float lgsum[9];

    float* part = (float*)hs;                 // [64][4][9] f32
    float* rwp  = (float*)hs + 2304;          // 160*9 f32

    int tid = threadIdx.x;
    int base = blockIdx.x * 64;

    for (int i = tid; i < 160 * 9; i += 256) rwp[i] = rweights[i];
    if (tid < 9) { lcount[tid] = 0u; lgsum[tid] = 0.f; }
    __syncthreads();

    int tok = tid >> 2, sub = tid & 3;
    {
        float acc[9];
        #pragma unroll
        for (int e = 0; e < 9; ++e) acc[e] = 0.f;
        const float* xrow = x + (size_t)(base + tok) * 128 + sub * 32;
        for (int d = 0; d < 32; ++d) {
            float xv = xrow[d];
            #pragma unroll
            for (int e = 0; e < 9; ++e) acc[e] += xv * rwp[(sub * 32 + d) * 9 + e];
        }
        #pragma unroll
        for (int e = 0; e < 9; ++e) part[(tok * 4 + sub) * 9 + e] = acc[e];
    }
    if (tid < 9) {
        float c = rb[tid];
        float wlb = Wlb[0];
        for (int m = 0; m < 32; ++m) c += (mg[m] + wlb) * rwp[(128 + m) * 9 + tid];
        ce[tid] = c;
    }
    // stage X -> swizzled bf16 LDS
    {
        const float4* x4 = (const float4*)x;
        for (int i = tid; i < 64 * 32; i += 256) {
            int row = i >> 5, p = i & 31;
            float4 v = x4[(size_t)(base + row) * 32 + p];
            unsigned short u[4] = { f2bf(v.x), f2bf(v.y), f2bf(v.z), f2bf(v.w) };
            int sw = ((((p >> 1) ^ (row & 7)) << 4) | ((p & 1) << 3));
            *(ushort4*)((char*)xs + row * 256 + sw) = *(ushort4*)u;
        }
    }
    __syncthreads();

    if (sub == 0) {
        float lg[9];
        #pragma unroll
        for (int e = 0; e < 9; ++e)
            lg[e] = ce[e] + part[(tok * 4 + 0) * 9 + e] + part[(tok * 4 + 1) * 9 + e]
                  + part[(tok * 4 + 2) * 9 + e] + part[(tok * 4 + 3) * 9 + e];
        int used = 0;
        int bi[3]; float bv[3];
        for (int k = 0; k < 3; ++k) {
            float best = -1e30f; int b = -1;
            for (int e = 0; e < 9; ++e)
                if (!((used >> e) & 1) && lg[e] > best) { best = lg[e]; b = e; }
            bi[k] = b; bv[k] = best; used |= 1 << b;
        }
        float p3[3]; float s = 0.f;
        for (int k = 0; k < 3; ++k) { p3[k] = expf(bv[k] - bv[0]); s += p3[k]; }
        #pragma unroll
        for (int e = 0; e < 12; ++e) garr[tok][e] = 0.f;
        for (int k = 0; k < 3; ++k) {
            float g = p3[k] / s;
            garr[tok][bi[k]] = g;
            atomicAdd(&lcount[bi[k]], 1u);
            atomicAdd(&lgsum[bi[k]], g);
        }
    }
    __syncthreads();   // garr ready; hs (part/rwp) free
    if (tid < 9) {
        atomicAdd(&cnt[tid], lcount[tid]);
        atomicAdd(&gsum[tid], lgsum[tid]);
    }

    int lane = tid & 63, w = tid >> 6;
    int cb = lane & 15, kq = lane >> 4;

    f32x4 acc_out[4][2];
    #pragma unroll
    for (int m = 0; m < 4; ++m)
        #pragma unroll
        for (int nn = 0; nn < 2; ++nn) acc_out[m][nn] = (f32x4){0.f, 0.f, 0.f, 0.f};

    #pragma unroll 1
    for (int e = 0; e < 9; ++e) {
        const unsigned short* B1 = W1F + (size_t)e * 16384 + (w * 2) * 2048 + lane * 8;
        const unsigned short* B2 = W2F + (size_t)e * 16384 + (w * 2) * 2048 + lane * 8;

        // Phase 1: acc1 = X @ W1x (this wave's 32 cols)
        bf16x8 b1f[2][4];
        #pragma unroll
        for (int nn = 0; nn < 2; ++nn)
            #pragma unroll
            for (int kk = 0; kk < 4; ++kk)
                b1f[nn][kk] = *(const bf16x8*)(B1 + nn * 2048 + kk * 512);

        f32x4 acc1[4][2];
        #pragma unroll
        for (int m = 0; m < 4; ++m)
            #pragma unroll
            for (int nn = 0; nn < 2; ++nn) acc1[m][nn] = (f32x4){0.f, 0.f, 0.f, 0.f};

        #pragma unroll
        for (int m = 0; m < 4; ++m) {
            int arow = m * 16 + cb;
            #pragma unroll
            for (int kk = 0; kk < 4; ++kk) {
                bf16x8 a = *(const bf16x8*)((const char*)xs + arow * 256 + ((((kk * 4 + kq) ^ (arow & 7)) << 4)));
                acc1[m][0] = __builtin_amdgcn_mfma_f32_16x16x32_bf16(a, b1f[0][kk], acc1[m][0], 0, 0, 0);
                acc1[m][1] = __builtin_amdgcn_mfma_f32_16x16x32_bf16(a, b1f[1][kk], acc1[m][1], 0, 0, 0);
            }
        }

        // epilogue: H = relu(acc1 + sb) * gate -> hs (swizzled bf16)
        #pragma unroll
        for (int nn = 0; nn < 2; ++nn) {
            int col = (w * 2 + nn) * 16 + cb;
            float sbv = sbg[e * 128 + col];
            int chunk = (col * 2) >> 4;      // byte>>4
            int boff  = (col * 2) & 15;
            #pragma unroll
            for (int m = 0; m < 4; ++m) {
                #pragma unroll
                for (int r = 0; r < 4; ++r) {
                    int row = m * 16 + kq * 4 + r;
                    float h = acc1[m][nn][r] + sbv;
                    h = (h > 0.f ? h : 0.f) * garr[row][e];
                    int sw = (((chunk ^ (row & 7)) << 4) | boff);
                    *(unsigned short*)((char*)hs + row * 256 + sw) = f2bf(h);
                }
            }
        }
        __syncthreads();

        // Phase 2: acc_out += H @ W2 (this wave's 32 cols, K=128)
        bf16x8 b2f[2][4];
        #pragma unroll
        for (int nn = 0; nn < 2; ++nn)
            #pragma unroll
            for (int kk = 0; kk < 4; ++kk)
                b2f[nn][kk] = *(const bf16x8*)(B2 + nn * 2048 + kk * 512);

        #pragma unroll
        for (int m = 0; m < 4; ++m) {
            int arow = m * 16 + cb;
            #pragma unroll
            for (int kk = 0; kk < 4; ++kk) {
                bf16x8 a = *(const bf16x8*)((const char*)hs + arow * 256 + ((((kk * 4 + kq) ^ (arow & 7)) << 4)));
                acc_out[m][0] = __builtin_amdgcn_mfma_f32_16x16x32_bf16(a, b2f[0][kk], acc_out[m][0], 0, 0, 0);
                acc_out[m][1] = __builtin_amdgcn_mfma_f32_16x16x32_bf16(a, b2f[1][kk], acc_out[m][1], 0, 0, 0);
            }
        }
        __syncthreads();   // hs consumed; next expert may overwrite
    }

    // final: add sum_e g[row][e]*b2[e][col], store
    #pragma unroll
    for (int nn = 0; nn < 2; ++nn) {
        int col = (w * 2 + nn) * 16 + cb;
        float b2c[9];
        #pragma unroll
        for (int e = 0; e < 9; ++e) b2c[e] = b2g[e * 128 + col];
        #pragma unroll
        for (int m = 0; m < 4; ++m) {
            #pragma unroll
            for (int r = 0; r < 4; ++r) {
                int row = m * 16 + kq * 4 + r;
                float bias = 0.f;
                #pragma unroll
                for (int e = 0; e < 9; ++e) bias += garr[row][e] * b2c[e];
                out[(size_t)(base + row) * 128 + col] = acc_out[m][nn][r] + bias;
            }
        }
    }
}

extern "C" void kernel_launch(void* const* d_in, const int* in_sizes, int n_in,
                              void* d_out, int out_size, void* d_ws, size_t ws_size,
                              hipStream_t stream) {
    const float* x      = (const float*)d_in[0];
    const float* Wrw    = (const float*)d_in[1];
    const float* Wrb    = (const float*)d_in[2];
    const float* Wlw    = (const float*)d_in[3];
    const float* Wlb    = (const float*)d_in[4];
    const float* rw     = (const float*)d_in[5];
    const float* rb     = (const float*)d_in[6];
    const float* styles = (const float*)d_in[7];
    const float* W1     = (const float*)d_in[8];
    const float* b1     = (const float*)d_in[9];
    const float* W2     = (const float*)d_in[10];
    const float* b2     = (const float*)d_in[11];
    float* out = (float*)d_out;

    char* ws = (char*)d_ws;
    float*          mg    = (float*)(ws + OFF_MG);
    unsigned*       cnt   = (unsigned*)(ws + OFF_CNT);
    float*          gsum  = (float*)(ws + OFF_GSUM);
    float*          sbp   = (float*)(ws + OFF_SB);
    unsigned short* W1F   = (unsigned short*)(ws + OFF_W1F);
    unsigned short* W2F   = (unsigned short*)(ws + OFF_W2F);

    hipMemsetAsync(ws, 0, 256, stream);   // mg, cnt, gsum

    k_market<<<1024, 256, 0, stream>>>(x, Wrw, Wrb, Wlw, mg);
    k_prepw<<<dim3(9, 8), 256, 0, stream>>>(W1, W2, W1F, W2F);
    k_stylebias<<<9, 128, 0, stream>>>(styles, W1, b1, sbp);
    k_fused<<<1024, 256, 0, stream>>>(x, rw, rb, mg, Wlb, W1F, W2F, sbp, b2,
                                      cnt, gsum, out);
    k_aux<<<1, 1, 0, stream>>>(cnt, gsum, out);
}

// Round 7
// 199.327 us; speedup vs baseline: 2.4113x; 1.0810x over previous
//
#include <hip/hip_runtime.h>
#include <hip/hip_bf16.h>
#include <math.h>

#define NTOK 65536
#define DIM  128
#define NE   9
#define TOPK 3
#define ALPHA_C 1e-4f

using bf16x8 = __attribute__((ext_vector_type(8))) short;
using f32x4  = __attribute__((ext_vector_type(4))) float;

// ws layout (bytes)
static constexpr size_t OFF_MG   = 0;        // 32 f32
static constexpr size_t OFF_CNT  = 128;      // 9 u32
static constexpr size_t OFF_GSUM = 192;      // 9 f32
static constexpr size_t OFF_SB   = 256;      // 9*128 f32 -> 4864
static constexpr size_t OFF_W1F  = 4864;     // 9*128*128 bf16 (frag-ordered) -> 299776
static constexpr size_t OFF_W2F  = 299776;   // -> 594688

__device__ __forceinline__ unsigned short f2bf(float f) {
    __hip_bfloat16 h = __float2bfloat16(f);
    return *reinterpret_cast<unsigned short*>(&h);
}

// ---------------- K1: market = relu(x@Wr_w + Wr_b); mg[m] = sum_n market[n][m]*Wl_w[n]
// xs stride padded 128->132: unpadded read xs[tok*128+d] was a 16-way same-bank conflict.
__global__ __launch_bounds__(256) void k_market(const float* __restrict__ x,
    const float* __restrict__ Wrw, const float* __restrict__ Wrb,
    const float* __restrict__ Wlw, float* __restrict__ mg_acc)
{
    __shared__ float xs[64 * 132];
    __shared__ float wr[128 * 32];
    __shared__ float part[256][8];
    int tid = threadIdx.x;
    int base = blockIdx.x * 64;

    const float4* x4 = (const float4*)x + (size_t)base * 32;
    for (int i = tid; i < 64 * 32; i += 256) {
        int row = i >> 5, c4 = i & 31;
        *(float4*)(&xs[row * 132 + c4 * 4]) = x4[i];
    }
    const float4* w4 = (const float4*)Wrw;
    float4* wr4 = (float4*)wr;
    for (int i = tid; i < 128 * 32 / 4; i += 256) wr4[i] = w4[i];
    __syncthreads();

    int tok = tid >> 2, sub = tid & 3, m0 = sub * 8;
    float acc[8];
    #pragma unroll
    for (int k = 0; k < 8; ++k) acc[k] = 0.f;
    for (int d = 0; d < 128; ++d) {
        float xv = xs[tok * 132 + d];
        #pragma unroll
        for (int k = 0; k < 8; ++k) acc[k] += xv * wr[d * 32 + m0 + k];
    }
    float wl = Wlw[base + tok];
    #pragma unroll
    for (int k = 0; k < 8; ++k) {
        float v = acc[k] + Wrb[m0 + k];
        part[tid][k] = (v > 0.f ? v : 0.f) * wl;
    }
    __syncthreads();
    if (tid < 32) {
        int m = tid;
        float s = 0.f;
        for (int t = 0; t < 64; ++t) s += part[t * 4 + (m >> 3)][m & 7];
        atomicAdd(&mg_acc[m], s);
    }
}

// ---------------- K_prepw: fragment-ordered bf16 weights.
// WF[e][mt][kk][lane][j] = W[e][kk*32+(lane>>4)*8+j][mt*16+(lane&15)]
// Serves as A-frag of W^T (row=mt*16+(l&15), k=kk*32+(l>>4)*8+j): one
// coalesced 1KB load per (mt,kk) per wave.
__global__ __launch_bounds__(256) void k_prepw(const float* __restrict__ W1,
    const float* __restrict__ W2, unsigned short* __restrict__ W1F,
    unsigned short* __restrict__ W2F)
{
    int e = blockIdx.x;
    int n = blockIdx.y;
    int tid = threadIdx.x;
    int kk = tid >> 6, l = tid & 63;
    int row0 = kk * 32 + (l >> 4) * 8;
    int col  = n * 16 + (l & 15);
    const float* W1e = W1 + (size_t)e * 20480;   // [160][128]
    const float* W2e = W2 + (size_t)e * 16384;   // [128][128]
    size_t ob = (size_t)e * 16384 + n * 2048 + kk * 512 + l * 8;
    unsigned short u1[8], u2[8];
    #pragma unroll
    for (int j = 0; j < 8; ++j) {
        u1[j] = f2bf(W1e[(size_t)(row0 + j) * 128 + col]);
        u2[j] = f2bf(W2e[(size_t)(row0 + j) * 128 + col]);
    }
    *(ushort4*)(W1F + ob)     = *(ushort4*)(u1);
    *(ushort4*)(W1F + ob + 4) = *(ushort4*)(u1 + 4);
    *(ushort4*)(W2F + ob)     = *(ushort4*)(u2);
    *(ushort4*)(W2F + ob + 4) = *(ushort4*)(u2 + 4);
}

// ---------------- K4: style_bias[e][h]
__global__ void k_stylebias(const float* __restrict__ styles, const float* __restrict__ W1,
                            const float* __restrict__ b1, float* __restrict__ sb)
{
    int e = blockIdx.x, h = threadIdx.x;
    float acc = b1[e * 128 + h];
    for (int s = 0; s < 32; ++s)
        acc += styles[e * 32 + s] * W1[(size_t)e * 20480 + (size_t)(128 + s) * 128 + h];
    sb[e * 128 + h] = acc;
}

// ---------------- K3: aux loss scalar
__global__ void k_aux(const unsigned* __restrict__ cnt, const float* __restrict__ gsum,
                      float* __restrict__ out)
{
    float a = 0.f;
    for (int e = 0; e < 9; ++e) {
        float fi = (float)cnt[e] * ((float)NE / ((float)TOPK * (float)NTOK));
        float Pi = gsum[e] / (float)NTOK;
        a += fi * Pi;
    }
    out[(size_t)NTOK * DIM] = ALPHA_C * a;
}

// ---------------- K_fused: router + dense 9-expert FFN, transposed GEMM space.
// Computes H^T = W1x^T @ X^T and O^T = W2^T @ H^T per expert (M=h/d=128,
// N=tok=64, K=128). A = frag-ordered W (global), B = row-major swizzled
// xs/hs (b128 conflict-free). Wave w owns M-tiles {2w,2w+1}, all 4 N-tiles.
// hs double-buffered: 1 barrier per expert.
__global__ __launch_bounds__(256) void k_fused(const float* __restrict__ x,
    const float* __restrict__ rweights, const float* __restrict__ rb,
    const float* __restrict__ mg, const float* __restrict__ Wlb,
    const unsigned short* __restrict__ W1F, const unsigned short* __restrict__ W2F,
    const float* __restrict__ sbg, const float* __restrict__ b2g,
    unsigned* __restrict__ cnt, float* __restrict__ gsum,
    float* __restrict__ out)
{
    __shared__ unsigned short xs[64 * 128];      // 16 KB swizzled bf16 X
    __shared__ unsigned short hs[2][64 * 128];   // 32 KB swizzled bf16 H (dbuf)
    __shared__ float garr[64][12];
    __shared__ float ce[9];
    __shared__ unsigned lcount[9];
    __shared__ float lgsum[9];

    float* part = (float*)hs;                 // [64][4][9] f32 overlay (router)
    float* rwp  = (float*)hs + 2304;          // 160*9 f32 -> 14976 B < 16 KB

    int tid = threadIdx.x;
    int base = blockIdx.x * 64;

    for (int i = tid; i < 160 * 9; i += 256) rwp[i] = rweights[i];
    if (tid < 9) { lcount[tid] = 0u; lgsum[tid] = 0.f; }
    __syncthreads();

    int tok = tid >> 2, sub = tid & 3;
    {
        float acc[9];
        #pragma unroll
        for (int e = 0; e < 9; ++e) acc[e] = 0.f;
        const float* xrow = x + (size_t)(base + tok) * 128 + sub * 32;
        for (int d = 0; d < 32; ++d) {
            float xv = xrow[d];
            #pragma unroll
            for (int e = 0; e < 9; ++e) acc[e] += xv * rwp[(sub * 32 + d) * 9 + e];
        }
        #pragma unroll
        for (int e = 0; e < 9; ++e) part[(tok * 4 + sub) * 9 + e] = acc[e];
    }
    if (tid < 9) {
        float c = rb[tid];
        float wlb = Wlb[0];
        for (int m = 0; m < 32; ++m) c += (mg[m] + wlb) * rwp[(128 + m) * 9 + tid];
        ce[tid] = c;
    }
    // stage X -> swizzled bf16 LDS (row t, chunk c at byte ((c^(t&7))<<4))
    {
        const float4* x4 = (const float4*)x;
        for (int i = tid; i < 64 * 32; i += 256) {
            int row = i >> 5, p = i & 31;
            float4 v = x4[(size_t)(base + row) * 32 + p];
            unsigned short u[4] = { f2bf(v.x), f2bf(v.y), f2bf(v.z), f2bf(v.w) };
            int sw = ((((p >> 1) ^ (row & 7)) << 4) | ((p & 1) << 3));
            *(ushort4*)((char*)xs + row * 256 + sw) = *(ushort4*)u;
        }
    }
    __syncthreads();

    if (sub == 0) {
        float lg[9];
        #pragma unroll
        for (int e = 0; e < 9; ++e)
            lg[e] = ce[e] + part[(tok * 4 + 0) * 9 + e] + part[(tok * 4 + 1) * 9 + e]
                  + part[(tok * 4 + 2) * 9 + e] + part[(tok * 4 + 3) * 9 + e];
        int used = 0;
        int bi[3]; float bv[3];
        for (int k = 0; k < 3; ++k) {
            float best = -1e30f; int b = -1;
            for (int e = 0; e < 9; ++e)
                if (!((used >> e) & 1) && lg[e] > best) { best = lg[e]; b = e; }
            bi[k] = b; bv[k] = best; used |= 1 << b;
        }
        float p3[3]; float s = 0.f;
        for (int k = 0; k < 3; ++k) { p3[k] = expf(bv[k] - bv[0]); s += p3[k]; }
        #pragma unroll
        for (int e = 0; e < 12; ++e) garr[tok][e] = 0.f;
        for (int k = 0; k < 3; ++k) {
            float g = p3[k] / s;
            garr[tok][bi[k]] = g;
            atomicAdd(&lcount[bi[k]], 1u);
            atomicAdd(&lgsum[bi[k]], g);
        }
    }
    __syncthreads();   // garr ready; hs free
    if (tid < 9) {
        atomicAdd(&cnt[tid], lcount[tid]);
        atomicAdd(&gsum[tid], lgsum[tid]);
    }

    int lane = tid & 63, w = tid >> 6;
    int tl = lane & 15;     // token-within-Ntile (B col / C col)
    int hq = lane >> 4;     // quarter (A k-slice / C row group)
    int xr = tl & 7;        // swizzle xor term (row&7 for rows t=Ntile*16+tl)

    f32x4 acc_out[2][4];
    #pragma unroll
    for (int mi = 0; mi < 2; ++mi)
        #pragma unroll
        for (int ni = 0; ni < 4; ++ni) acc_out[mi][ni] = (f32x4){0.f, 0.f, 0.f, 0.f};

    #pragma unroll 1
    for (int e = 0; e < 9; ++e) {
        const unsigned short* A1 = W1F + (size_t)e * 16384 + (w * 2) * 2048 + lane * 8;
        const unsigned short* A2 = W2F + (size_t)e * 16384 + (w * 2) * 2048 + lane * 8;
        unsigned short* cur = hs[e & 1];

        // A-frags for phase 1 (W1x^T): 8 coalesced 1KB loads
        bf16x8 a1[2][4];
        #pragma unroll
        for (int mi = 0; mi < 2; ++mi)
            #pragma unroll
            for (int kk = 0; kk < 4; ++kk)
                a1[mi][kk] = *(const bf16x8*)(A1 + mi * 2048 + kk * 512);

        // acc1 init = style_bias (C-in): row h = (w*2+mi)*16 + hq*4 + r
        float4 sbv0 = *(const float4*)(sbg + e * 128 + (w * 2 + 0) * 16 + hq * 4);
        float4 sbv1 = *(const float4*)(sbg + e * 128 + (w * 2 + 1) * 16 + hq * 4);
        f32x4 acc1[2][4];
        #pragma unroll
        for (int ni = 0; ni < 4; ++ni) {
            acc1[0][ni] = (f32x4){sbv0.x, sbv0.y, sbv0.z, sbv0.w};
            acc1[1][ni] = (f32x4){sbv1.x, sbv1.y, sbv1.z, sbv1.w};
        }

        // Phase 1: H^T = W1x^T @ X^T (+sb). B-frag: row t=ni*16+tl, chunk kk*4+hq
        #pragma unroll
        for (int kk = 0; kk < 4; ++kk) {
            #pragma unroll
            for (int ni = 0; ni < 4; ++ni) {
                bf16x8 b = *(const bf16x8*)((const char*)xs + (ni * 16 + tl) * 256
                               + ((((kk * 4 + hq) ^ xr) << 4)));
                acc1[0][ni] = __builtin_amdgcn_mfma_f32_16x16x32_bf16(a1[0][kk], b, acc1[0][ni], 0, 0, 0);
                acc1[1][ni] = __builtin_amdgcn_mfma_f32_16x16x32_bf16(a1[1][kk], b, acc1[1][ni], 0, 0, 0);
            }
        }

        // A-frags for phase 2 issued now: latency hides under epilogue+barrier
        bf16x8 a2[2][4];
        #pragma unroll
        for (int mi = 0; mi < 2; ++mi)
            #pragma unroll
            for (int kk = 0; kk < 4; ++kk)
                a2[mi][kk] = *(const bf16x8*)(A2 + mi * 2048 + kk * 512);

        // Epilogue 1: H = relu(acc1)*g -> hs[t][h], 4 consecutive h = ds_write_b64
        #pragma unroll
        for (int ni = 0; ni < 4; ++ni) {
            int t = ni * 16 + tl;
            float g = garr[t][e];
            char* rowp = (char*)cur + t * 256;
            #pragma unroll
            for (int mi = 0; mi < 2; ++mi) {
                f32x4 v = acc1[mi][ni];
                unsigned short u[4];
                u[0] = f2bf(fmaxf(v[0], 0.f) * g);
                u[1] = f2bf(fmaxf(v[1], 0.f) * g);
                u[2] = f2bf(fmaxf(v[2], 0.f) * g);
                u[3] = f2bf(fmaxf(v[3], 0.f) * g);
                int chunk = (w * 2 + mi) * 2 + (hq >> 1);
                int off = (hq & 1) * 8;
                *(ushort4*)(rowp + (((chunk ^ xr) << 4) | off)) = *(ushort4*)u;
            }
        }
        __syncthreads();   // hs[cur] complete; prior buffer's readers already synced

        // Phase 2: O^T += W2^T @ H^T
        #pragma unroll
        for (int kk = 0; kk < 4; ++kk) {
            #pragma unroll
            for (int ni = 0; ni < 4; ++ni) {
                bf16x8 b = *(const bf16x8*)((const char*)cur + (ni * 16 + tl) * 256
                               + ((((kk * 4 + hq) ^ xr) << 4)));
                acc_out[0][ni] = __builtin_amdgcn_mfma_f32_16x16x32_bf16(a2[0][kk], b, acc_out[0][ni], 0, 0, 0);
                acc_out[1][ni] = __builtin_amdgcn_mfma_f32_16x16x32_bf16(a2[1][kk], b, acc_out[1][ni], 0, 0, 0);
            }
        }
    }

    // Final: out[t][d] = acc_out + sum_e g[t][e]*b2[e][d]; float4 stores
    #pragma unroll
    for (int mi = 0; mi < 2; ++mi) {
        int d0 = (w * 2 + mi) * 16 + hq * 4;
        float4 b2v[9];
        #pragma unroll
        for (int e = 0; e < 9; ++e) b2v[e] = *(const float4*)(b2g + e * 128 + d0);
        #pragma unroll
        for (int ni = 0; ni < 4; ++ni) {
            int t = ni * 16 + tl;
            float4 bias = {0.f, 0.f, 0.f, 0.f};
            #pragma unroll
            for (int e = 0; e < 9; ++e) {
                float g = garr[t][e];
                bias.x += g * b2v[e].x; bias.y += g * b2v[e].y;
                bias.z += g * b2v[e].z; bias.w += g * b2v[e].w;
            }
            f32x4 v = acc_out[mi][ni];
            float4 r = {v[0] + bias.x, v[1] + bias.y, v[2] + bias.z, v[3] + bias.w};
            *(float4*)(out + (size_t)(base + t) * 128 + d0) = r;
        }
    }
}

extern "C" void kernel_launch(void* const* d_in, const int* in_sizes, int n_in,
                              void* d_out, int out_size, void* d_ws, size_t ws_size,
                              hipStream_t stream) {
    const float* x      = (const float*)d_in[0];
    const float* Wrw    = (const float*)d_in[1];
    const float* Wrb    = (const float*)d_in[2];
    const float* Wlw    = (const float*)d_in[3];
    const float* Wlb    = (const float*)d_in[4];
    const float* rw     = (const float*)d_in[5];
    const float* rb     = (const float*)d_in[6];
    const float* styles = (const float*)d_in[7];
    const float* W1     = (const float*)d_in[8];
    const float* b1     = (const float*)d_in[9];
    const float* W2     = (const float*)d_in[10];
    const float* b2     = (const float*)d_in[11];
    float* out = (float*)d_out;

    char* ws = (char*)d_ws;
    float*          mg    = (float*)(ws + OFF_MG);
    unsigned*       cnt   = (unsigned*)(ws + OFF_CNT);
    float*          gsum  = (float*)(ws + OFF_GSUM);
    float*          sbp   = (float*)(ws + OFF_SB);
    unsigned short* W1F   = (unsigned short*)(ws + OFF_W1F);
    unsigned short* W2F   = (unsigned short*)(ws + OFF_W2F);

    hipMemsetAsync(ws, 0, 256, stream);   // mg, cnt, gsum

    k_market<<<1024, 256, 0, stream>>>(x, Wrw, Wrb, Wlw, mg);
    k_prepw<<<dim3(9, 8), 256, 0, stream>>>(W1, W2, W1F, W2F);
    k_stylebias<<<9, 128, 0, stream>>>(styles, W1, b1, sbp);
    k_fused<<<1024, 256, 0, stream>>>(x, rw, rb, mg, Wlb, W1F, W2F, sbp, b2,
                                      cnt, gsum, out);
    k_aux<<<1, 1, 0, stream>>>(cnt, gsum, out);
}

// Round 8
// 190.927 us; speedup vs baseline: 2.5174x; 1.0440x over previous
//
#include <hip/hip_runtime.h>
#include <hip/hip_bf16.h>
#include <math.h>

#define NTOK 65536
#define DIM  128
#define NE   9
#define TOPK 3
#define ALPHA_C 1e-4f

using bf16x8 = __attribute__((ext_vector_type(8))) short;
using f32x4  = __attribute__((ext_vector_type(4))) float;

// ws layout (bytes)
static constexpr size_t OFF_MG   = 0;        // 32 f32
static constexpr size_t OFF_CNT  = 128;      // 9 u32
static constexpr size_t OFF_GSUM = 192;      // 9 f32
static constexpr size_t OFF_SB   = 256;      // 9*128 f32 -> 4864
static constexpr size_t OFF_W1F  = 4864;     // 9*128*128 bf16 (frag-ordered) -> 299776
static constexpr size_t OFF_W2F  = 299776;   // -> 594688

__device__ __forceinline__ unsigned short f2bf(float f) {
    __hip_bfloat16 h = __float2bfloat16(f);
    return *reinterpret_cast<unsigned short*>(&h);
}

// ---------------- K_prep: fused {market(1024) | prepw(72) | stylebias(9)} by block range
__global__ __launch_bounds__(256) void k_prep(const float* __restrict__ x,
    const float* __restrict__ Wrw, const float* __restrict__ Wrb,
    const float* __restrict__ Wlw, float* __restrict__ mg_acc,
    const float* __restrict__ W1, const float* __restrict__ W2,
    unsigned short* __restrict__ W1F, unsigned short* __restrict__ W2F,
    const float* __restrict__ styles, const float* __restrict__ b1,
    float* __restrict__ sb)
{
    __shared__ float smem[64 * 132 + 128 * 32];   // xs[64][132] + wr[128][32] = 49 KB
    __shared__ float wpart[4][32];
    int bid = blockIdx.x;
    int tid = threadIdx.x;

    if (bid < 1024) {
        // ---- market: market = relu(x@Wr+b); mg[m] += sum market[n][m]*wl[n]
        float* xs = smem;            // [64][132] (pad: 16-way -> 2-way)
        float* wr = smem + 64 * 132; // [128][32]
        int base = bid * 64;
        const float4* x4g = (const float4*)x + (size_t)base * 32;
        for (int i = tid; i < 2048; i += 256) {
            int row = i >> 5, c = i & 31;
            *(float4*)(xs + row * 132 + c * 4) = x4g[i];
        }
        for (int i = tid; i < 1024; i += 256)
            ((float4*)wr)[i] = ((const float4*)Wrw)[i];
        __syncthreads();

        int lane = tid & 63, wv = tid >> 6;
        int tok = wv * 16 + (lane >> 2), sub = lane & 3, m0 = sub * 8;
        float acc[8];
        #pragma unroll
        for (int k = 0; k < 8; ++k) acc[k] = 0.f;
        for (int c = 0; c < 32; ++c) {
            float4 xv = *(const float4*)(xs + tok * 132 + c * 4);
            float xa[4] = {xv.x, xv.y, xv.z, xv.w};
            #pragma unroll
            for (int dd = 0; dd < 4; ++dd)
                #pragma unroll
                for (int k = 0; k < 8; ++k)
                    acc[k] += xa[dd] * wr[(c * 4 + dd) * 32 + m0 + k];
        }
        float wl = Wlw[base + tok];
        #pragma unroll
        for (int k = 0; k < 8; ++k) {
            float v = acc[k] + Wrb[m0 + k];
            acc[k] = (v > 0.f ? v : 0.f) * wl;
        }
        // reduce over the 16 tokens in the wave (lane bits 2..5)
        #pragma unroll
        for (int off = 4; off <= 32; off <<= 1)
            #pragma unroll
            for (int k = 0; k < 8; ++k)
                acc[k] += __shfl_xor(acc[k], off);
        if (lane < 4)
            #pragma unroll
            for (int k = 0; k < 8; ++k) wpart[wv][lane * 8 + k] = acc[k];
        __syncthreads();
        if (tid < 32) {
            float s = wpart[0][tid] + wpart[1][tid] + wpart[2][tid] + wpart[3][tid];
            atomicAdd(&mg_acc[tid], s);
        }
    } else if (bid < 1096) {
        // ---- prepw: frag-ordered bf16 weights
        // WF[e][mt][kk][lane][j] = W[e][kk*32+(lane>>4)*8+j][mt*16+(lane&15)]
        int b = bid - 1024;
        int e = b >> 3, n = b & 7;
        int kk = tid >> 6, l = tid & 63;
        int row0 = kk * 32 + (l >> 4) * 8;
        int col  = n * 16 + (l & 15);
        const float* W1e = W1 + (size_t)e * 20480;   // [160][128]
        const float* W2e = W2 + (size_t)e * 16384;   // [128][128]
        size_t ob = (size_t)e * 16384 + n * 2048 + kk * 512 + l * 8;
        unsigned short u1[8], u2[8];
        #pragma unroll
        for (int j = 0; j < 8; ++j) {
            u1[j] = f2bf(W1e[(size_t)(row0 + j) * 128 + col]);
            u2[j] = f2bf(W2e[(size_t)(row0 + j) * 128 + col]);
        }
        *(ushort4*)(W1F + ob)     = *(ushort4*)(u1);
        *(ushort4*)(W1F + ob + 4) = *(ushort4*)(u1 + 4);
        *(ushort4*)(W2F + ob)     = *(ushort4*)(u2);
        *(ushort4*)(W2F + ob + 4) = *(ushort4*)(u2 + 4);
    } else {
        // ---- stylebias
        int e = bid - 1096;
        if (tid < 128) {
            int h = tid;
            float acc = b1[e * 128 + h];
            for (int s = 0; s < 32; ++s)
                acc += styles[e * 32 + s] * W1[(size_t)e * 20480 + (size_t)(128 + s) * 128 + h];
            sb[e * 128 + h] = acc;
        }
    }
}

// ---------------- K3: aux loss scalar
__global__ void k_aux(const unsigned* __restrict__ cnt, const float* __restrict__ gsum,
                      float* __restrict__ out)
{
    float a = 0.f;
    for (int e = 0; e < 9; ++e) {
        float fi = (float)cnt[e] * ((float)NE / ((float)TOPK * (float)NTOK));
        float Pi = gsum[e] / (float)NTOK;
        a += fi * Pi;
    }
    out[(size_t)NTOK * DIM] = ALPHA_C * a;
}

// ---------------- K_fused: router + dense 9-expert FFN, transposed GEMM space.
// H^T = W1x^T @ X^T, O^T = W2^T @ H^T. A = frag-ordered W (global, coalesced),
// B = swizzled LDS xs/hs. Single hs buffer (LDS ~35.5 KB -> 4 blocks/CU),
// 2 barriers per expert.
__global__ __launch_bounds__(256) void k_fused(const float* __restrict__ x,
    const float* __restrict__ rweights, const float* __restrict__ rb,
    const float* __restrict__ mg, const float* __restrict__ Wlb,
    const unsigned short* __restrict__ W1F, const unsigned short* __restrict__ W2F,
    const float* __restrict__ sbg, const float* __restrict__ b2g,
    unsigned* __restrict__ cnt, float* __restrict__ gsum,
    float* __restrict__ out)
{
    __shared__ unsigned short xs[64 * 128];   // 16 KB swizzled bf16 X
    __shared__ unsigned short hs[64 * 128];   // 16 KB swizzled bf16 H; router overlay
    __shared__ float garr[64][12];
    __shared__ float ce[9];
    __shared__ unsigned lcount[9];
    __shared__ float lgsum[9];

    float* part = (float*)hs;                 // [64][4][9] f32
    float* rwp  = (float*)hs + 2304;          // 160*9 f32 -> 14976 B < 16 KB

    int tid = threadIdx.x;
    int base = blockIdx.x * 64;

    for (int i = tid; i < 160 * 9; i += 256) rwp[i] = rweights[i];
    if (tid < 9) { lcount[tid] = 0u; lgsum[tid] = 0.f; }
    __syncthreads();

    // router partials: 4 threads/token, d-interleaved (sub-addresses differ by
    // 9 dwords -> distinct banks; old sub*32 split was 4-way same-bank)
    int tok = tid >> 2, sub = tid & 3;
    {
        float acc[9];
        #pragma unroll
        for (int e = 0; e < 9; ++e) acc[e] = 0.f;
        const float* xrow = x + (size_t)(base + tok) * 128 + sub;
        for (int d = 0; d < 32; ++d) {
            float xv = xrow[d * 4];
            #pragma unroll
            for (int e = 0; e < 9; ++e) acc[e] += xv * rwp[(d * 4 + sub) * 9 + e];
        }
        #pragma unroll
        for (int e = 0; e < 9; ++e) part[(tok * 4 + sub) * 9 + e] = acc[e];
    }
    if (tid < 9) {
        float c = rb[tid];
        float wlb = Wlb[0];
        for (int m = 0; m < 32; ++m) c += (mg[m] + wlb) * rwp[(128 + m) * 9 + tid];
        ce[tid] = c;
    }
    // stage X -> swizzled bf16 LDS
    {
        const float4* x4 = (const float4*)x;
        for (int i = tid; i < 64 * 32; i += 256) {
            int row = i >> 5, p = i & 31;
            float4 v = x4[(size_t)(base + row) * 32 + p];
            unsigned short u[4] = { f2bf(v.x), f2bf(v.y), f2bf(v.z), f2bf(v.w) };
            int sw = ((((p >> 1) ^ (row & 7)) << 4) | ((p & 1) << 3));
            *(ushort4*)((char*)xs + row * 256 + sw) = *(ushort4*)u;
        }
    }
    __syncthreads();

    if (sub == 0) {
        float lg[9];
        #pragma unroll
        for (int e = 0; e < 9; ++e)
            lg[e] = ce[e] + part[(tok * 4 + 0) * 9 + e] + part[(tok * 4 + 1) * 9 + e]
                  + part[(tok * 4 + 2) * 9 + e] + part[(tok * 4 + 3) * 9 + e];
        int used = 0;
        int bi[3]; float bv[3];
        for (int k = 0; k < 3; ++k) {
            float best = -1e30f; int b = -1;
            for (int e = 0; e < 9; ++e)
                if (!((used >> e) & 1) && lg[e] > best) { best = lg[e]; b = e; }
            bi[k] = b; bv[k] = best; used |= 1 << b;
        }
        float p3[3]; float s = 0.f;
        for (int k = 0; k < 3; ++k) { p3[k] = expf(bv[k] - bv[0]); s += p3[k]; }
        #pragma unroll
        for (int e = 0; e < 12; ++e) garr[tok][e] = 0.f;
        for (int k = 0; k < 3; ++k) {
            float g = p3[k] / s;
            garr[tok][bi[k]] = g;
            atomicAdd(&lcount[bi[k]], 1u);
            atomicAdd(&lgsum[bi[k]], g);
        }
    }
    __syncthreads();   // garr ready; hs (part/rwp) free
    if (tid < 9) {
        atomicAdd(&cnt[tid], lcount[tid]);
        atomicAdd(&gsum[tid], lgsum[tid]);
    }

    int lane = tid & 63, w = tid >> 6;
    int tl = lane & 15;     // token-within-Ntile
    int hq = lane >> 4;     // quarter
    int xr = tl & 7;        // swizzle xor term

    f32x4 acc_out[2][4];
    #pragma unroll
    for (int mi = 0; mi < 2; ++mi)
        #pragma unroll
        for (int ni = 0; ni < 4; ++ni) acc_out[mi][ni] = (f32x4){0.f, 0.f, 0.f, 0.f};

    #pragma unroll 1
    for (int e = 0; e < 9; ++e) {
        const unsigned short* A1 = W1F + (size_t)e * 16384 + (w * 2) * 2048 + lane * 8;
        const unsigned short* A2 = W2F + (size_t)e * 16384 + (w * 2) * 2048 + lane * 8;

        bf16x8 a1[2][4];
        #pragma unroll
        for (int mi = 0; mi < 2; ++mi)
            #pragma unroll
            for (int kk = 0; kk < 4; ++kk)
                a1[mi][kk] = *(const bf16x8*)(A1 + mi * 2048 + kk * 512);

        float4 sbv0 = *(const float4*)(sbg + e * 128 + (w * 2 + 0) * 16 + hq * 4);
        float4 sbv1 = *(const float4*)(sbg + e * 128 + (w * 2 + 1) * 16 + hq * 4);
        f32x4 acc1[2][4];
        #pragma unroll
        for (int ni = 0; ni < 4; ++ni) {
            acc1[0][ni] = (f32x4){sbv0.x, sbv0.y, sbv0.z, sbv0.w};
            acc1[1][ni] = (f32x4){sbv1.x, sbv1.y, sbv1.z, sbv1.w};
        }

        // Phase 1: H^T = W1x^T @ X^T (+sb)
        #pragma unroll
        for (int kk = 0; kk < 4; ++kk) {
            #pragma unroll
            for (int ni = 0; ni < 4; ++ni) {
                bf16x8 b = *(const bf16x8*)((const char*)xs + (ni * 16 + tl) * 256
                               + ((((kk * 4 + hq) ^ xr) << 4)));
                acc1[0][ni] = __builtin_amdgcn_mfma_f32_16x16x32_bf16(a1[0][kk], b, acc1[0][ni], 0, 0, 0);
                acc1[1][ni] = __builtin_amdgcn_mfma_f32_16x16x32_bf16(a1[1][kk], b, acc1[1][ni], 0, 0, 0);
            }
        }

        // A2 loads issued now: latency hides under epilogue
        bf16x8 a2[2][4];
        #pragma unroll
        for (int mi = 0; mi < 2; ++mi)
            #pragma unroll
            for (int kk = 0; kk < 4; ++kk)
                a2[mi][kk] = *(const bf16x8*)(A2 + mi * 2048 + kk * 512);

        // Epilogue 1: H = relu(acc1)*g -> hs (swizzled, b64 writes)
        #pragma unroll
        for (int ni = 0; ni < 4; ++ni) {
            int t = ni * 16 + tl;
            float g = garr[t][e];
            char* rowp = (char*)hs + t * 256;
            #pragma unroll
            for (int mi = 0; mi < 2; ++mi) {
                f32x4 v = acc1[mi][ni];
                unsigned short u[4];
                u[0] = f2bf(fmaxf(v[0], 0.f) * g);
                u[1] = f2bf(fmaxf(v[1], 0.f) * g);
                u[2] = f2bf(fmaxf(v[2], 0.f) * g);
                u[3] = f2bf(fmaxf(v[3], 0.f) * g);
                int chunk = (w * 2 + mi) * 2 + (hq >> 1);
                int off = (hq & 1) * 8;
                *(ushort4*)(rowp + (((chunk ^ xr) << 4) | off)) = *(ushort4*)u;
            }
        }
        __syncthreads();   // hs complete

        // Phase 2: O^T += W2^T @ H^T
        #pragma unroll
        for (int kk = 0; kk < 4; ++kk) {
            #pragma unroll
            for (int ni = 0; ni < 4; ++ni) {
                bf16x8 b = *(const bf16x8*)((const char*)hs + (ni * 16 + tl) * 256
                               + ((((kk * 4 + hq) ^ xr) << 4)));
                acc_out[0][ni] = __builtin_amdgcn_mfma_f32_16x16x32_bf16(a2[0][kk], b, acc_out[0][ni], 0, 0, 0);
                acc_out[1][ni] = __builtin_amdgcn_mfma_f32_16x16x32_bf16(a2[1][kk], b, acc_out[1][ni], 0, 0, 0);
            }
        }
        if (e != 8) __syncthreads();   // hs consumed before next epilogue overwrites
    }

    // Final: out[t][d] = acc_out + sum_e g[t][e]*b2[e][d]
    #pragma unroll
    for (int mi = 0; mi < 2; ++mi) {
        int d0 = (w * 2 + mi) * 16 + hq * 4;
        float4 b2v[9];
        #pragma unroll
        for (int e = 0; e < 9; ++e) b2v[e] = *(const float4*)(b2g + e * 128 + d0);
        #pragma unroll
        for (int ni = 0; ni < 4; ++ni) {
            int t = ni * 16 + tl;
            float4 bias = {0.f, 0.f, 0.f, 0.f};
            #pragma unroll
            for (int e = 0; e < 9; ++e) {
                float g = garr[t][e];
                bias.x += g * b2v[e].x; bias.y += g * b2v[e].y;
                bias.z += g * b2v[e].z; bias.w += g * b2v[e].w;
            }
            f32x4 v = acc_out[mi][ni];
            float4 r = {v[0] + bias.x, v[1] + bias.y, v[2] + bias.z, v[3] + bias.w};
            *(float4*)(out + (size_t)(base + t) * 128 + d0) = r;
        }
    }
}

extern "C" void kernel_launch(void* const* d_in, const int* in_sizes, int n_in,
                              void* d_out, int out_size, void* d_ws, size_t ws_size,
                              hipStream_t stream) {
    const float* x      = (const float*)d_in[0];
    const float* Wrw    = (const float*)d_in[1];
    const float* Wrb    = (const float*)d_in[2];
    const float* Wlw    = (const float*)d_in[3];
    const float* Wlb    = (const float*)d_in[4];
    const float* rw     = (const float*)d_in[5];
    const float* rb     = (const float*)d_in[6];
    const float* styles = (const float*)d_in[7];
    const float* W1     = (const float*)d_in[8];
    const float* b1     = (const float*)d_in[9];
    const float* W2     = (const float*)d_in[10];
    const float* b2     = (const float*)d_in[11];
    float* out = (float*)d_out;

    char* ws = (char*)d_ws;
    float*          mg    = (float*)(ws + OFF_MG);
    unsigned*       cnt   = (unsigned*)(ws + OFF_CNT);
    float*          gsum  = (float*)(ws + OFF_GSUM);
    float*          sbp   = (float*)(ws + OFF_SB);
    unsigned short* W1F   = (unsigned short*)(ws + OFF_W1F);
    unsigned short* W2F   = (unsigned short*)(ws + OFF_W2F);

    hipMemsetAsync(ws, 0, 256, stream);   // mg, cnt, gsum

    k_prep<<<1105, 256, 0, stream>>>(x, Wrw, Wrb, Wlw, mg, W1, W2, W1F, W2F,
                                     styles, b1, sbp);
    k_fused<<<1024, 256, 0, stream>>>(x, rw, rb, mg, Wlb, W1F, W2F, sbp, b2,
                                      cnt, gsum, out);
    k_aux<<<1, 1, 0, stream>>>(cnt, gsum, out);
}